// Round 12
// baseline (602.225 us; speedup 1.0000x reference)
//
#include <hip/hip_runtime.h>
#include <hip/hip_bf16.h>

// N=8192, D=512.  Q = emb@Wqk^T+bqk (K==Q); out = softmax(QK^T/sqrt(512)) @ V.
// Softmax rows sum to 1 => out = (softmax(S)@emb) @ Wv^T + bv (V never built).
// Device dtype runtime-detected (fp32 observed). Internal: bf16 MFMA, fp32 acc.
// R11 post-mortem: attn64 (Tq=64) sits exactly at the ~7 TB/s cache wall
// (2.15 GB traffic); traffic scales 1/Tq. R12: Tq=128 trimmed to fit the
// 128-VGPR cap (kb/vb 2-at-a-time, accS[4], accO[8][2]) -- R10's spill came
// from ~12 regs over. Partials bf16 (ws stays 48.2MB <= proven 64MB), lsum
// via LDS cross-wave reduce (no atomics, R11-proven). transpose fused into
// projq (same staged tile writes Q and embT). 4 launches.

#define NTOK 8192
#define DIM  512

typedef unsigned short ushort_t;
typedef __attribute__((ext_vector_type(8))) __bf16 bf16x8;
typedef __attribute__((ext_vector_type(4))) float f32x4;

__device__ __forceinline__ float bf2f(ushort_t u) {
    union { unsigned int i; float f; } v; v.i = ((unsigned int)u) << 16; return v.f;
}
__device__ __forceinline__ ushort_t f2bf(float f) {
    union { float f; unsigned int i; } v; v.f = f;
    unsigned int b = v.i;
    return (ushort_t)((b + 0x7FFFu + ((b >> 16) & 1u)) >> 16);   // RNE
}
__device__ __forceinline__ __bf16 f2bfh(float f) {
    union { ushort_t u; __bf16 h; } c; c.u = f2bf(f); return c.h;
}
__device__ __forceinline__ f32x4 mfma16(bf16x8 a, bf16x8 b, f32x4 c) {
    return __builtin_amdgcn_mfma_f32_16x16x32_bf16(a, b, c, 0, 0, 0);
}
__device__ __forceinline__ bf16x8 load8(const void* p, size_t idx, bool f32) {
    if (f32) {
        const float* f = (const float*)p + idx;
        bf16x8 r;
        #pragma unroll
        for (int j = 0; j < 8; ++j) r[j] = f2bfh(f[j]);
        return r;
    }
    return *(const bf16x8*)((const ushort_t*)p + idx);
}
__device__ __forceinline__ float loadS(const void* p, size_t idx, bool f32) {
    return f32 ? ((const float*)p)[idx] : bf2f(((const ushort_t*)p)[idx]);
}

#define LDA 520   // 260 dw, %32=4: uniform 2 dw/bank for b128 row reads
#define LDP 264

// ---------------------------------------------------------------------------
// Dtype probe: flag=1 => bf16 data, flag=0 => fp32.
// ---------------------------------------------------------------------------
__global__ void detect_kernel(const ushort_t* __restrict__ emb, int* __restrict__ flag)
{
    int lane = threadIdx.x;
    int cnt = 0;
    #pragma unroll
    for (int i = 0; i < 8; ++i) {
        ushort_t u = emb[(size_t)(lane * 8 + i) * 2];
        int a = u & 0x7FFF;
        int e = (u >> 7) & 0xFF;
        if (a == 0 || (e >= 111 && e <= 143)) cnt++;
    }
    cnt += __shfl_xor(cnt, 1);  cnt += __shfl_xor(cnt, 2);  cnt += __shfl_xor(cnt, 4);
    cnt += __shfl_xor(cnt, 8);  cnt += __shfl_xor(cnt, 16); cnt += __shfl_xor(cnt, 32);
    if (lane == 0) *flag = (cnt >= 460) ? 1 : 0;
}

// ---------------------------------------------------------------------------
// Fused: Q[8192][512](bf16) = emb @ Wqk^T + bqk  AND  embT[512][8192](bf16)
// = emb^T, both from one staged 32x512 tile.  256 blocks x 512 thr.
// ---------------------------------------------------------------------------
__global__ __launch_bounds__(512)
void projqT_kernel(const int* __restrict__ flag, const void* __restrict__ emb,
                   const void* __restrict__ W, const void* __restrict__ bias,
                   ushort_t* __restrict__ C, ushort_t* __restrict__ embT)
{
    __shared__ ushort_t Alds[32][LDA];
    const bool f32 = (*flag == 0);
    const int tid  = threadIdx.x;
    const int wave = tid >> 6;
    const int lane = tid & 63;
    const int quad = lane >> 4;
    const int col  = lane & 15;
    const int mblk = blockIdx.x * 32;

    #pragma unroll
    for (int i = 0; i < 4; ++i) {
        int chunk = i * 512 + tid;
        int row = chunk >> 6;
        int k8  = (chunk & 63) * 8;
        *(bf16x8*)&Alds[row][k8] = load8(emb, (size_t)(mblk + row) * 512 + k8, f32);
    }
    __syncthreads();

    // ---- transpose write: thread t owns dim d=t, 32 tokens (64 B store) ----
    {
        ushort_t buf[32];
        #pragma unroll
        for (int r = 0; r < 32; ++r) buf[r] = Alds[r][tid];
        ushort_t* dst = embT + (size_t)tid * NTOK + mblk;
        #pragma unroll
        for (int i = 0; i < 4; ++i)
            *(uint4*)(dst + i * 8) = *(uint4*)&buf[i * 8];
    }

    // ---- Q projection ----
    f32x4 acc[2][4];
    #pragma unroll
    for (int r = 0; r < 2; ++r)
        #pragma unroll
        for (int c = 0; c < 4; ++c) acc[r][c] = (f32x4){0.f, 0.f, 0.f, 0.f};

    const int wcol = wave * 64;
    #pragma unroll
    for (int kk = 0; kk < 16; ++kk) {
        bf16x8 a0 = *(const bf16x8*)&Alds[col][kk * 32 + quad * 8];
        bf16x8 a1 = *(const bf16x8*)&Alds[16 + col][kk * 32 + quad * 8];
        #pragma unroll
        for (int c = 0; c < 4; ++c) {
            bf16x8 b = load8(W, (size_t)(wcol + c * 16 + col) * 512 + kk * 32 + quad * 8, f32);
            acc[0][c] = mfma16(a0, b, acc[0][c]);
            acc[1][c] = mfma16(a1, b, acc[1][c]);
        }
    }

    #pragma unroll
    for (int r = 0; r < 2; ++r)
        #pragma unroll
        for (int c = 0; c < 4; ++c)
            #pragma unroll
            for (int g = 0; g < 4; ++g) {
                int m = mblk + r * 16 + quad * 4 + g;
                int n = wcol + c * 16 + col;
                C[(size_t)m * DIM + n] = f2bf(acc[r][c][g] + loadS(bias, n, f32));
            }
}

// ---------------------------------------------------------------------------
// Attention partials, Tq=128 (register-trimmed): 256 blocks = 64 q-tiles x
// 4 key-splits (2048 keys), 1024 thr = 16 waves, KT=128/iter (16 iters).
// Wave w: S for keys [16(w&7),+16) x rows [64(w>>3),+64) (accS[4]);
// owns D cols [32w,+32) in PV (accO[8][2]=64 acc regs).
// kb/vb loaded 2-at-a-time (peak regs ~116 <= 128). Qlds XOR-swizzled 128KB;
// Plds 16KB two-phase (R10-verified layout). bf16 partial stores (disjoint,
// full coverage); lsum via cross-wave LDS reduce. No atomics.
// ---------------------------------------------------------------------------
__global__ __launch_bounds__(1024)
void attn128_kernel(const ushort_t* __restrict__ Q, const ushort_t* __restrict__ embT,
                    ushort_t* __restrict__ Pall, float* __restrict__ lsumA)
{
    __shared__ ushort_t Qlds[128 * 512];   // 131,072 B, swizzled chunk^(row&7)
    __shared__ ushort_t Plds[128 * 64];    //  16,384 B, one 64-key phase
    __shared__ float    Lp[16][64];        //   4,096 B

    const int tid  = threadIdx.x;
    const int wave = tid >> 6;
    const int lane = tid & 63;
    const int quad = lane >> 4;
    const int col  = lane & 15;
    const int qt   = blockIdx.x >> 2;
    const int ks   = blockIdx.x & 3;
    const int q0   = qt * 128;
    const int kb0  = ks * 2048;
    ushort_t* Ps = Pall + (size_t)ks * NTOK * DIM;

    {   // stage Q tile 128x512 bf16 swizzled: thread t -> row t>>3, 8 chunks
        const int row = tid >> 3;
        const ushort_t* src = &Q[(size_t)(q0 + row) * 512];
        ushort_t* dst = &Qlds[row * 512];
        const int sw = (row & 7) * 8;
        const int cb = (tid & 7) * 64;
        #pragma unroll
        for (int i = 0; i < 8; ++i) {
            int c8 = cb + i * 8;
            *(bf16x8*)&dst[c8 ^ sw] = *(const bf16x8*)&src[c8];
        }
    }
    __syncthreads();

    f32x4 accO[8][2];
    #pragma unroll
    for (int r = 0; r < 8; ++r)
        #pragma unroll
        for (int c = 0; c < 2; ++c) accO[r][c] = (f32x4){0.f, 0.f, 0.f, 0.f};

    float lsum[4][4];
    #pragma unroll
    for (int r = 0; r < 4; ++r)
        #pragma unroll
        for (int g = 0; g < 4; ++g) lsum[r][g] = 0.f;

    const float sc = 0.04419417382415922f * 1.4426950408889634f;  // 1/sqrt(512)*log2e
    const int kg = wave & 7;     // key-group (16 of 128 keys)
    const int rg = wave >> 3;    // row-group (64 of 128 rows)
    const int wd = wave * 32;    // owned D-col base in PV
    const int colsw = (col & 7) * 8;

    for (int it = 0; it < 16; ++it) {
        const int j0 = kb0 + it * 128;

        // ---- S(rg's 64 rows x kg's 16 keys), kb 2-at-a-time ----
        f32x4 accS[4];
        #pragma unroll
        for (int r = 0; r < 4; ++r) accS[r] = (f32x4){0.f, 0.f, 0.f, 0.f};
        const size_t keyrow = (size_t)(j0 + kg * 16 + col) * 512;
        #pragma unroll
        for (int kc2 = 0; kc2 < 8; ++kc2) {
            bf16x8 kA = *(const bf16x8*)&Q[keyrow + (kc2 * 2) * 32 + quad * 8];
            bf16x8 kB = *(const bf16x8*)&Q[keyrow + (kc2 * 2 + 1) * 32 + quad * 8];
            #pragma unroll
            for (int k = 0; k < 2; ++k) {
                const int cofs = (kc2 * 2 + k) * 32 + quad * 8;
                bf16x8 kb8 = k ? kB : kA;
                #pragma unroll
                for (int r = 0; r < 4; ++r) {
                    bf16x8 a = *(const bf16x8*)&Qlds[(rg * 64 + r * 16 + col) * 512
                                                     + (cofs ^ colsw)];
                    accS[r] = mfma16(a, kb8, accS[r]);
                }
            }
        }

        // ---- P = exp2(S*sc) in-register; accumulate row sums ----
        #pragma unroll
        for (int r = 0; r < 4; ++r)
            #pragma unroll
            for (int g = 0; g < 4; ++g) {
                float v = exp2f(fminf(accS[r][g] * sc, 126.0f));
                accS[r][g] = v;
                lsum[r][g] += v;
            }

        // ---- two 64-key phases (R10-verified layout) ----
        #pragma unroll
        for (int ph = 0; ph < 2; ++ph) {
            if ((kg >> 2) == ph) {
                const int klb = (kg & 3) * 16;
                #pragma unroll
                for (int r = 0; r < 4; ++r)
                    #pragma unroll
                    for (int g = 0; g < 4; ++g) {
                        int prow = rg * 64 + r * 16 + quad * 4 + g;
                        int kl   = klb + col;
                        int kch  = kl >> 3;
                        Plds[prow * 64 + (((kch ^ (prow & 7)) << 3) | (kl & 7))]
                            = f2bf(accS[r][g]);
                    }
            }
            __syncthreads();

            #pragma unroll
            for (int kf = 0; kf < 2; ++kf) {
                const size_t kgl = (size_t)j0 + ph * 64 + kf * 32 + quad * 8;
                bf16x8 vb0 = *(const bf16x8*)&embT[(size_t)(wd + col) * NTOK + kgl];
                bf16x8 vb1 = *(const bf16x8*)&embT[(size_t)(wd + 16 + col) * NTOK + kgl];
                #pragma unroll
                for (int r = 0; r < 8; ++r) {
                    int prow = r * 16 + col;
                    bf16x8 a = *(const bf16x8*)&Plds[prow * 64
                                  + (((kf * 4 + quad) ^ (prow & 7)) << 3)];
                    accO[r][0] = mfma16(a, vb0, accO[r][0]);
                    accO[r][1] = mfma16(a, vb1, accO[r][1]);
                }
            }
            __syncthreads();
        }
    }

    // ---- row sums: lane-reduce then cross-wave LDS reduce (no atomics) ----
    #pragma unroll
    for (int r = 0; r < 4; ++r)
        #pragma unroll
        for (int g = 0; g < 4; ++g) {
            float s = lsum[r][g];
            s += __shfl_xor(s, 1);
            s += __shfl_xor(s, 2);
            s += __shfl_xor(s, 4);
            s += __shfl_xor(s, 8);
            if (col == 0)
                Lp[wave][r * 16 + quad * 4 + g] = s;
        }
    __syncthreads();
    if (tid < 128) {
        int rgl = tid >> 6;
        float t = 0.f;
        #pragma unroll
        for (int k = 0; k < 8; ++k) t += Lp[rgl * 8 + k][tid & 63];
        lsumA[(size_t)ks * NTOK + q0 + tid] = t;
    }

    // ---- bf16 partial store (disjoint, full 128x512 coverage) ----
    #pragma unroll
    for (int r = 0; r < 8; ++r)
        #pragma unroll
        for (int c = 0; c < 2; ++c)
            #pragma unroll
            for (int g = 0; g < 4; ++g)
                Ps[(size_t)(q0 + r * 16 + quad * 4 + g) * DIM + wd + c * 16 + col]
                    = f2bf(accO[r][c][g]);
}

// ---------------------------------------------------------------------------
// Finalize: T = (sum of 4 bf16 partials)/(sum of 4 lsums), out = T@Wv^T + bv.
// 256 blocks x 512 thr, 32 rows/block.
// ---------------------------------------------------------------------------
__global__ __launch_bounds__(512)
void finalize_kernel(const int* __restrict__ flag, const ushort_t* __restrict__ Pall,
                     const float* __restrict__ lsumA,
                     const void* __restrict__ Wv, const void* __restrict__ bv,
                     void* __restrict__ Out)
{
    __shared__ ushort_t Alds[32][LDA];
    const bool f32 = (*flag == 0);
    const int tid  = threadIdx.x;
    const int wave = tid >> 6;
    const int lane = tid & 63;
    const int quad = lane >> 4;
    const int col  = lane & 15;
    const int mblk = blockIdx.x * 32;

    #pragma unroll
    for (int i = 0; i < 4; ++i) {
        int chunk = i * 512 + tid;
        int row = chunk >> 6;
        int k8  = (chunk & 63) * 8;
        int m   = mblk + row;
        float rv = 1.0f / (lsumA[m] + lsumA[NTOK + m] + lsumA[2 * NTOK + m]
                           + lsumA[3 * NTOK + m]);
        float s[8];
        #pragma unroll
        for (int j = 0; j < 8; ++j) s[j] = 0.f;
        #pragma unroll
        for (int t = 0; t < 4; ++t) {
            bf16x8 v = *(const bf16x8*)&Pall[(size_t)t * NTOK * DIM + (size_t)m * 512 + k8];
            #pragma unroll
            for (int j = 0; j < 8; ++j) s[j] += (float)v[j];
        }
        bf16x8 o;
        #pragma unroll
        for (int j = 0; j < 8; ++j) o[j] = f2bfh(s[j] * rv);
        *(bf16x8*)&Alds[row][k8] = o;
    }
    __syncthreads();

    f32x4 acc[2][4];
    #pragma unroll
    for (int r = 0; r < 2; ++r)
        #pragma unroll
        for (int c = 0; c < 4; ++c) acc[r][c] = (f32x4){0.f, 0.f, 0.f, 0.f};

    const int wcol = wave * 64;
    #pragma unroll
    for (int kk = 0; kk < 16; ++kk) {
        bf16x8 a0 = *(const bf16x8*)&Alds[col][kk * 32 + quad * 8];
        bf16x8 a1 = *(const bf16x8*)&Alds[16 + col][kk * 32 + quad * 8];
        #pragma unroll
        for (int c = 0; c < 4; ++c) {
            bf16x8 b = load8(Wv, (size_t)(wcol + c * 16 + col) * 512 + kk * 32 + quad * 8, f32);
            acc[0][c] = mfma16(a0, b, acc[0][c]);
            acc[1][c] = mfma16(a1, b, acc[1][c]);
        }
    }

    #pragma unroll
    for (int r = 0; r < 2; ++r)
        #pragma unroll
        for (int c = 0; c < 4; ++c)
            #pragma unroll
            for (int g = 0; g < 4; ++g) {
                int m = mblk + r * 16 + quad * 4 + g;
                int n = wcol + c * 16 + col;
                float v = acc[r][c][g] + loadS(bv, n, f32);
                if (f32) ((float*)Out)[(size_t)m * DIM + n] = v;
                else     ((ushort_t*)Out)[(size_t)m * DIM + n] = f2bf(v);
            }
}

// ---------------------------------------------------------------------------
// Fallback fused attention (R6-proven) for smaller workspaces.
// ---------------------------------------------------------------------------
template <int VT>
__global__ __launch_bounds__(1024)
void attn_fused_kernel(const int* __restrict__ flag, const ushort_t* __restrict__ Q,
                       const void* __restrict__ embOrT, const void* __restrict__ Wv,
                       const void* __restrict__ bv, void* __restrict__ Out)
{
    __shared__ ushort_t Qlds[32][LDA];
    __shared__ ushort_t Plds[2][32][LDP];
    __shared__ float    Lpart[16][32];

    const bool f32 = (*flag == 0);
    const int tid  = threadIdx.x;
    const int wave = tid >> 6;
    const int lane = tid & 63;
    const int quad = lane >> 4;
    const int col  = lane & 15;
    const int q0   = blockIdx.x * 32;

    #pragma unroll
    for (int i = 0; i < 2; ++i) {
        int chunk = i * 1024 + tid;
        int row = chunk >> 6;
        int k8  = (chunk & 63) * 8;
        *(bf16x8*)&Qlds[row][k8] = *(const bf16x8*)&Q[(size_t)(q0 + row) * 512 + k8];
    }
    __syncthreads();

    f32x4 accO[2][2];
    #pragma unroll
    for (int r = 0; r < 2; ++r)
        #pragma unroll
        for (int c = 0; c < 2; ++c) accO[r][c] = (f32x4){0.f, 0.f, 0.f, 0.f};

    float lsum[2][4];
    #pragma unroll
    for (int r = 0; r < 2; ++r)
        #pragma unroll
        for (int g = 0; g < 4; ++g) lsum[r][g] = 0.f;

    const float sc = 0.04419417382415922f * 1.4426950408889634f;
    const int wOcol = wave * 32;

    for (int it = 0; it < 32; ++it) {
        const int j0  = it * 256;
        const int buf = it & 1;

        bf16x8 kb[16];
        const size_t keyrow = (size_t)(j0 + wave * 16 + col) * 512;
        #pragma unroll
        for (int kk = 0; kk < 16; ++kk)
            kb[kk] = *(const bf16x8*)&Q[keyrow + kk * 32 + quad * 8];

        f32x4 accS[2];
        accS[0] = (f32x4){0.f, 0.f, 0.f, 0.f};
        accS[1] = (f32x4){0.f, 0.f, 0.f, 0.f};
        #pragma unroll
        for (int kk = 0; kk < 16; ++kk) {
            bf16x8 a0 = *(const bf16x8*)&Qlds[col][kk * 32 + quad * 8];
            bf16x8 a1 = *(const bf16x8*)&Qlds[16 + col][kk * 32 + quad * 8];
            accS[0] = mfma16(a0, kb[kk], accS[0]);
            accS[1] = mfma16(a1, kb[kk], accS[1]);
        }

        bf16x8 vb[16];
        #pragma unroll
        for (int kk = 0; kk < 8; ++kk)
            #pragma unroll
            for (int c = 0; c < 2; ++c) {
                if (VT) {
                    vb[kk * 2 + c] = *(const bf16x8*)((const ushort_t*)embOrT
                        + (size_t)(wOcol + c * 16 + col) * NTOK + j0 + kk * 32 + quad * 8);
                } else {
                    size_t base = (size_t)(j0 + kk * 32 + quad * 8) * 512 + (wOcol + c * 16 + col);
                    bf16x8 b;
                    if (f32) {
                        const float* bp = (const float*)embOrT + base;
                        #pragma unroll
                        for (int j = 0; j < 8; ++j) b[j] = f2bfh(bp[(size_t)j * 512]);
                    } else {
                        const __bf16* bp = (const __bf16*)embOrT + base;
                        #pragma unroll
                        for (int j = 0; j < 8; ++j) b[j] = bp[(size_t)j * 512];
                    }
                    vb[kk * 2 + c] = b;
                }
            }

        #pragma unroll
        for (int r = 0; r < 2; ++r)
            #pragma unroll
            for (int g = 0; g < 4; ++g) {
                float p = exp2f(fminf(accS[r][g] * sc, 126.0f));
                lsum[r][g] += p;
                Plds[buf][r * 16 + quad * 4 + g][wave * 16 + col] = f2bf(p);
            }

        __syncthreads();

        #pragma unroll
        for (int kk = 0; kk < 8; ++kk) {
            bf16x8 a0 = *(const bf16x8*)&Plds[buf][col][kk * 32 + quad * 8];
            bf16x8 a1 = *(const bf16x8*)&Plds[buf][16 + col][kk * 32 + quad * 8];
            #pragma unroll
            for (int c = 0; c < 2; ++c) {
                accO[0][c] = mfma16(a0, vb[kk * 2 + c], accO[0][c]);
                accO[1][c] = mfma16(a1, vb[kk * 2 + c], accO[1][c]);
            }
        }
    }

    #pragma unroll
    for (int r = 0; r < 2; ++r)
        #pragma unroll
        for (int g = 0; g < 4; ++g) {
            float s = lsum[r][g];
            s += __shfl_xor(s, 1);
            s += __shfl_xor(s, 2);
            s += __shfl_xor(s, 4);
            s += __shfl_xor(s, 8);
            lsum[r][g] = s;
        }
    if (col == 0) {
        #pragma unroll
        for (int r = 0; r < 2; ++r)
            #pragma unroll
            for (int g = 0; g < 4; ++g)
                Lpart[wave][r * 16 + quad * 4 + g] = lsum[r][g];
    }
    __syncthreads();

    #pragma unroll
    for (int r = 0; r < 2; ++r) {
        float rinv[4];
        #pragma unroll
        for (int g = 0; g < 4; ++g) {
            float t = 0.f;
            #pragma unroll
            for (int w = 0; w < 16; ++w) t += Lpart[w][r * 16 + quad * 4 + g];
            rinv[g] = 1.0f / t;
        }
        #pragma unroll
        for (int c = 0; c < 2; ++c)
            #pragma unroll
            for (int g = 0; g < 4; ++g)
                Qlds[r * 16 + quad * 4 + g][wOcol + c * 16 + col] = f2bf(accO[r][c][g] * rinv[g]);
    }
    __syncthreads();

    f32x4 acc2[2][2];
    #pragma unroll
    for (int r = 0; r < 2; ++r)
        #pragma unroll
        for (int c = 0; c < 2; ++c) acc2[r][c] = (f32x4){0.f, 0.f, 0.f, 0.f};

    #pragma unroll
    for (int kk = 0; kk < 16; ++kk) {
        bf16x8 a0 = *(const bf16x8*)&Qlds[col][kk * 32 + quad * 8];
        bf16x8 a1 = *(const bf16x8*)&Qlds[16 + col][kk * 32 + quad * 8];
        #pragma unroll
        for (int c = 0; c < 2; ++c) {
            bf16x8 b = load8(Wv, (size_t)(wOcol + c * 16 + col) * 512 + kk * 32 + quad * 8, f32);
            acc2[0][c] = mfma16(a0, b, acc2[0][c]);
            acc2[1][c] = mfma16(a1, b, acc2[1][c]);
        }
    }

    #pragma unroll
    for (int r = 0; r < 2; ++r)
        #pragma unroll
        for (int c = 0; c < 2; ++c)
            #pragma unroll
            for (int g = 0; g < 4; ++g) {
                int m = q0 + r * 16 + quad * 4 + g;
                int n = wOcol + c * 16 + col;
                float v = acc2[r][c][g] + loadS(bv, n, f32);
                if (f32) ((float*)Out)[(size_t)m * DIM + n] = v;
                else     ((ushort_t*)Out)[(size_t)m * DIM + n] = f2bf(v);
            }
}

extern "C" void kernel_launch(void* const* d_in, const int* in_sizes, int n_in,
                              void* d_out, int out_size, void* d_ws, size_t ws_size,
                              hipStream_t stream)
{
    const void* emb = d_in[0];
    const void* Wqk = d_in[1];
    const void* bqk = d_in[2];
    const void* Wv  = d_in[3];
    const void* bv  = d_in[4];

    char* W = (char*)d_ws;
    int*      flag  = (int*)W;
    float*    lsumA = (float*)(W + 64);                        // 4x8192 fp32 = 128 KB
    ushort_t* embT  = (ushort_t*)(W + 64 + 131072);            // 8 MB
    ushort_t* Qws   = embT + (size_t)DIM * NTOK;               // 8 MB
    ushort_t* Pall  = Qws + (size_t)DIM * NTOK;                // 4 x 8 MB bf16 partials

    const size_t needA = 64 + 131072 + 2 * (size_t)NTOK * DIM * 2
                       + 4 * (size_t)NTOK * DIM * 2;           // ~48.2 MB (ws>=64MB proven)
    const size_t needB = 64 + 2 * (size_t)NTOK * DIM * 2;      // 16.03 MB

    detect_kernel<<<dim3(1), dim3(64), 0, stream>>>((const ushort_t*)emb, flag);

    if (ws_size >= needA) {
        projqT_kernel<<<dim3(NTOK / 32), dim3(512), 0, stream>>>(flag, emb, Wqk, bqk,
                                                                 Qws, embT);
        attn128_kernel<<<dim3(256), dim3(1024), 0, stream>>>(Qws, embT, Pall, lsumA);
        finalize_kernel<<<dim3(NTOK / 32), dim3(512), 0, stream>>>(flag, Pall, lsumA,
                                                                   Wv, bv, d_out);
    } else if (ws_size >= needB) {
        ushort_t* embT2 = (ushort_t*)(W + 64);
        ushort_t* Qws2  = embT2 + (size_t)DIM * NTOK;
        projqT_kernel<<<dim3(NTOK / 32), dim3(512), 0, stream>>>(flag, emb, Wqk, bqk,
                                                                 Qws2, embT2);
        attn_fused_kernel<1><<<dim3(NTOK / 32), dim3(1024), 0, stream>>>(
            flag, Qws2, embT2, Wv, bv, d_out);
    } else {
        ushort_t* Qsm = (ushort_t*)(W + 64);
        // projqT needs an embT target; without room, fall back to plain projq
        // behavior by writing embT into Qsm? No -- use gather path: stage Q only.
        projqT_kernel<<<dim3(NTOK / 32), dim3(512), 0, stream>>>(flag, emb, Wqk, bqk,
                                                                 Qsm, Qsm);  // embT unused
        attn_fused_kernel<0><<<dim3(NTOK / 32), dim3(1024), 0, stream>>>(
            flag, Qsm, emb, Wv, bv, d_out);
    }
}

// Round 13
// 411.302 us; speedup vs baseline: 1.4642x; 1.4642x over previous
//
#include <hip/hip_runtime.h>
#include <hip/hip_bf16.h>

// N=8192, D=512.  Q = emb@Wqk^T+bqk (K==Q); out = softmax(QK^T/sqrt(512)) @ V.
// Softmax rows sum to 1 => out = (softmax(S)@emb) @ Wv^T + bv (V never built).
// Device dtype runtime-detected (fp32 observed). Internal: bf16 MFMA, fp32 acc.
// R12 post-mortem: Tq=128/16-wave spills structurally (twice confirmed).
// R13 = R11 (best, 441us) made spill-free: kb 2x8 batches, vb split 8+8
// (vbB issued between P-write and barrier), bf16 partials (R12-validated,
// halves partial traffic), Plds double-buffer (1 barrier/iter).
// ws: 64B flag + 128KB lsum + embT 8MB + Q 8MB + 2x8MB bf16 partials = 32.1MB.

#define NTOK 8192
#define DIM  512

typedef unsigned short ushort_t;
typedef __attribute__((ext_vector_type(8))) __bf16 bf16x8;
typedef __attribute__((ext_vector_type(4))) float f32x4;

__device__ __forceinline__ float bf2f(ushort_t u) {
    union { unsigned int i; float f; } v; v.i = ((unsigned int)u) << 16; return v.f;
}
__device__ __forceinline__ ushort_t f2bf(float f) {
    union { float f; unsigned int i; } v; v.f = f;
    unsigned int b = v.i;
    return (ushort_t)((b + 0x7FFFu + ((b >> 16) & 1u)) >> 16);   // RNE
}
__device__ __forceinline__ __bf16 f2bfh(float f) {
    union { ushort_t u; __bf16 h; } c; c.u = f2bf(f); return c.h;
}
__device__ __forceinline__ f32x4 mfma16(bf16x8 a, bf16x8 b, f32x4 c) {
    return __builtin_amdgcn_mfma_f32_16x16x32_bf16(a, b, c, 0, 0, 0);
}
__device__ __forceinline__ bf16x8 load8(const void* p, size_t idx, bool f32) {
    if (f32) {
        const float* f = (const float*)p + idx;
        bf16x8 r;
        #pragma unroll
        for (int j = 0; j < 8; ++j) r[j] = f2bfh(f[j]);
        return r;
    }
    return *(const bf16x8*)((const ushort_t*)p + idx);
}
__device__ __forceinline__ float loadS(const void* p, size_t idx, bool f32) {
    return f32 ? ((const float*)p)[idx] : bf2f(((const ushort_t*)p)[idx]);
}

#define LDA 520   // 260 dw, %32=4: uniform 2 dw/bank for b128 row reads
#define LDP 264

// ---------------------------------------------------------------------------
// Dtype probe: flag=1 => bf16 data, flag=0 => fp32.
// ---------------------------------------------------------------------------
__global__ void detect_kernel(const ushort_t* __restrict__ emb, int* __restrict__ flag)
{
    int lane = threadIdx.x;
    int cnt = 0;
    #pragma unroll
    for (int i = 0; i < 8; ++i) {
        ushort_t u = emb[(size_t)(lane * 8 + i) * 2];
        int a = u & 0x7FFF;
        int e = (u >> 7) & 0xFF;
        if (a == 0 || (e >= 111 && e <= 143)) cnt++;
    }
    cnt += __shfl_xor(cnt, 1);  cnt += __shfl_xor(cnt, 2);  cnt += __shfl_xor(cnt, 4);
    cnt += __shfl_xor(cnt, 8);  cnt += __shfl_xor(cnt, 16); cnt += __shfl_xor(cnt, 32);
    if (lane == 0) *flag = (cnt >= 460) ? 1 : 0;
}

// ---------------------------------------------------------------------------
// embT[512][8192] (bf16) = emb^T.
// ---------------------------------------------------------------------------
__global__ __launch_bounds__(256)
void transpose_kernel(const int* __restrict__ flag, const void* __restrict__ emb,
                      ushort_t* __restrict__ embT)
{
    __shared__ float tile[64][65];
    const bool f32 = (*flag == 0);
    const int t  = threadIdx.x;
    const int j0 = blockIdx.x * 64;
    const int d0 = blockIdx.y * 64;
    {
        int r = t >> 2, cs = (t & 3) * 16;
        if (f32) {
            const float* src = (const float*)emb + (size_t)(j0 + r) * DIM + d0 + cs;
            #pragma unroll
            for (int i = 0; i < 16; i += 4) {
                float4 v = *(const float4*)(src + i);
                tile[r][cs + i]     = v.x;
                tile[r][cs + i + 1] = v.y;
                tile[r][cs + i + 2] = v.z;
                tile[r][cs + i + 3] = v.w;
            }
        } else {
            const ushort_t* src = (const ushort_t*)emb + (size_t)(j0 + r) * DIM + d0 + cs;
            #pragma unroll
            for (int i = 0; i < 16; ++i) tile[r][cs + i] = bf2f(src[i]);
        }
    }
    __syncthreads();
    {
        int d = t >> 2, js = (t & 3) * 16;
        ushort_t buf[16];
        #pragma unroll
        for (int i = 0; i < 16; ++i) buf[i] = f2bf(tile[js + i][d]);
        ushort_t* dst = embT + (size_t)(d0 + d) * NTOK + j0 + js;
        *(uint4*)dst       = *(uint4*)&buf[0];
        *(uint4*)(dst + 8) = *(uint4*)&buf[8];
    }
}

// ---------------------------------------------------------------------------
// Q[8192][512](bf16, ws) = emb @ Wqk^T + bqk.  512 thr, 8 waves.
// ---------------------------------------------------------------------------
__global__ __launch_bounds__(512)
void projq_kernel(const int* __restrict__ flag, const void* __restrict__ emb,
                  const void* __restrict__ W, const void* __restrict__ bias,
                  ushort_t* __restrict__ C)
{
    __shared__ ushort_t Alds[32][LDA];
    const bool f32 = (*flag == 0);
    const int tid  = threadIdx.x;
    const int wave = tid >> 6;
    const int lane = tid & 63;
    const int quad = lane >> 4;
    const int col  = lane & 15;
    const int mblk = blockIdx.x * 32;

    #pragma unroll
    for (int i = 0; i < 4; ++i) {
        int chunk = i * 512 + tid;
        int row = chunk >> 6;
        int k8  = (chunk & 63) * 8;
        *(bf16x8*)&Alds[row][k8] = load8(emb, (size_t)(mblk + row) * 512 + k8, f32);
    }
    __syncthreads();

    f32x4 acc[2][4];
    #pragma unroll
    for (int r = 0; r < 2; ++r)
        #pragma unroll
        for (int c = 0; c < 4; ++c) acc[r][c] = (f32x4){0.f, 0.f, 0.f, 0.f};

    const int wcol = wave * 64;
    #pragma unroll
    for (int kk = 0; kk < 16; ++kk) {
        bf16x8 a0 = *(const bf16x8*)&Alds[col][kk * 32 + quad * 8];
        bf16x8 a1 = *(const bf16x8*)&Alds[16 + col][kk * 32 + quad * 8];
        #pragma unroll
        for (int c = 0; c < 4; ++c) {
            bf16x8 b = load8(W, (size_t)(wcol + c * 16 + col) * 512 + kk * 32 + quad * 8, f32);
            acc[0][c] = mfma16(a0, b, acc[0][c]);
            acc[1][c] = mfma16(a1, b, acc[1][c]);
        }
    }

    #pragma unroll
    for (int r = 0; r < 2; ++r)
        #pragma unroll
        for (int c = 0; c < 4; ++c)
            #pragma unroll
            for (int g = 0; g < 4; ++g) {
                int m = mblk + r * 16 + quad * 4 + g;
                int n = wcol + c * 16 + col;
                C[(size_t)m * DIM + n] = f2bf(acc[r][c][g] + loadS(bias, n, f32));
            }
}

// ---------------------------------------------------------------------------
// Attention partials (R11 structure, spill-free): 256 blocks = 128 q-tiles
// (Tq=64) x 2 key-halves, 1024 thr = 16 waves, KT=256 (16 iters),
// double-buffered Plds (1 barrier/iter).
// Wave w: S for keys [16w,16w+16) x 64 rows; owns D cols [32w,32w+32) in PV.
// Register budget: accO 32 + accS 16 + lsum 16 + kb batch 32 / vbA+vbB 64
// (phased) ~ <=128. bf16 partial stores (disjoint, full coverage), lsum via
// cross-wave LDS reduce. No atomics.
// ---------------------------------------------------------------------------
__global__ __launch_bounds__(1024)
void attn64_kernel(const ushort_t* __restrict__ Q, const ushort_t* __restrict__ embT,
                   ushort_t* __restrict__ P0, ushort_t* __restrict__ P1,
                   float* __restrict__ lsumA)
{
    __shared__ ushort_t Qlds[64][LDA];       // 66,560 B
    __shared__ ushort_t Plds[2][64][LDP];    // 67,584 B (double buffer)
    __shared__ float    Lp[16][64];          //  4,096 B  -> 138,240 B total

    const int tid  = threadIdx.x;
    const int wave = tid >> 6;
    const int lane = tid & 63;
    const int quad = lane >> 4;
    const int col  = lane & 15;
    const int qt   = blockIdx.x & 127;
    const int ks   = blockIdx.x >> 7;
    const int q0   = qt * 64;
    const int kbase = ks * 4096;
    ushort_t* Ps = ks ? P1 : P0;

    #pragma unroll
    for (int i = 0; i < 4; ++i) {
        int chunk = i * 1024 + tid;
        int row = chunk >> 6;
        int k8  = (chunk & 63) * 8;
        *(bf16x8*)&Qlds[row][k8] = *(const bf16x8*)&Q[(size_t)(q0 + row) * 512 + k8];
    }
    __syncthreads();

    f32x4 accO[4][2];
    #pragma unroll
    for (int r = 0; r < 4; ++r)
        #pragma unroll
        for (int c = 0; c < 2; ++c) accO[r][c] = (f32x4){0.f, 0.f, 0.f, 0.f};

    float lsum[4][4];
    #pragma unroll
    for (int r = 0; r < 4; ++r)
        #pragma unroll
        for (int g = 0; g < 4; ++g) lsum[r][g] = 0.f;

    const float sc = 0.04419417382415922f * 1.4426950408889634f;  // 1/sqrt(512)*log2e
    const int wd = wave * 32;

    for (int it = 0; it < 16; ++it) {
        const int j0  = kbase + it * 256;
        const int buf = it & 1;

        // ---- S = Q_tile @ K^T, kb in 2 batches of 8 (32 VGPR transient) ----
        f32x4 accS[4];
        #pragma unroll
        for (int r = 0; r < 4; ++r) accS[r] = (f32x4){0.f, 0.f, 0.f, 0.f};
        const size_t keyrow = (size_t)(j0 + wave * 16 + col) * 512;
        #pragma unroll
        for (int h = 0; h < 2; ++h) {
            bf16x8 kb[8];
            #pragma unroll
            for (int kk = 0; kk < 8; ++kk)
                kb[kk] = *(const bf16x8*)&Q[keyrow + (h * 8 + kk) * 32 + quad * 8];
            #pragma unroll
            for (int kk = 0; kk < 8; ++kk) {
                const int cofs = (h * 8 + kk) * 32 + quad * 8;
                #pragma unroll
                for (int r = 0; r < 4; ++r) {
                    bf16x8 a = *(const bf16x8*)&Qlds[r * 16 + col][cofs];
                    accS[r] = mfma16(a, kb[kk], accS[r]);
                }
            }
        }

        // ---- vb batch A (kk 0..3, latency hides under exp + P-write) ----
        bf16x8 vbA[8];
        #pragma unroll
        for (int kk = 0; kk < 4; ++kk)
            #pragma unroll
            for (int c = 0; c < 2; ++c)
                vbA[kk * 2 + c] = *(const bf16x8*)&embT[
                    (size_t)(wd + c * 16 + col) * NTOK + j0 + kk * 32 + quad * 8];

        // ---- P = exp2(S*sc) -> Plds[buf] ----
        #pragma unroll
        for (int r = 0; r < 4; ++r)
            #pragma unroll
            for (int g = 0; g < 4; ++g) {
                float p = exp2f(fminf(accS[r][g] * sc, 126.0f));
                lsum[r][g] += p;
                Plds[buf][r * 16 + quad * 4 + g][wave * 16 + col] = f2bf(p);
            }

        // ---- vb batch B (kk 4..7, hides under barrier + PV first half) ----
        bf16x8 vbB[8];
        #pragma unroll
        for (int kk = 0; kk < 4; ++kk)
            #pragma unroll
            for (int c = 0; c < 2; ++c)
                vbB[kk * 2 + c] = *(const bf16x8*)&embT[
                    (size_t)(wd + c * 16 + col) * NTOK + j0 + (4 + kk) * 32 + quad * 8];

        __syncthreads();   // P(t) visible; buf reuse at distance 2 safe (R5/R6-proven)

        // ---- O += P @ V: first half consumes vbA, second vbB ----
        #pragma unroll
        for (int kk = 0; kk < 4; ++kk) {
            #pragma unroll
            for (int r = 0; r < 4; ++r) {
                bf16x8 a = *(const bf16x8*)&Plds[buf][r * 16 + col][kk * 32 + quad * 8];
                #pragma unroll
                for (int c = 0; c < 2; ++c)
                    accO[r][c] = mfma16(a, vbA[kk * 2 + c], accO[r][c]);
            }
        }
        #pragma unroll
        for (int kk = 0; kk < 4; ++kk) {
            #pragma unroll
            for (int r = 0; r < 4; ++r) {
                bf16x8 a = *(const bf16x8*)&Plds[buf][r * 16 + col][(4 + kk) * 32 + quad * 8];
                #pragma unroll
                for (int c = 0; c < 2; ++c)
                    accO[r][c] = mfma16(a, vbB[kk * 2 + c], accO[r][c]);
            }
        }
    }

    // ---- row sums: lane-reduce then cross-wave LDS reduce (no atomics) ----
    #pragma unroll
    for (int r = 0; r < 4; ++r)
        #pragma unroll
        for (int g = 0; g < 4; ++g) {
            float s = lsum[r][g];
            s += __shfl_xor(s, 1);
            s += __shfl_xor(s, 2);
            s += __shfl_xor(s, 4);
            s += __shfl_xor(s, 8);
            if (col == 0)
                Lp[wave][r * 16 + quad * 4 + g] = s;
        }
    __syncthreads();
    if (tid < 64) {
        float t = 0.f;
        #pragma unroll
        for (int w = 0; w < 16; ++w) t += Lp[w][tid];
        lsumA[(size_t)ks * NTOK + q0 + tid] = t;
    }

    // ---- bf16 partial store (disjoint, full 64x512 coverage) ----
    #pragma unroll
    for (int r = 0; r < 4; ++r)
        #pragma unroll
        for (int c = 0; c < 2; ++c)
            #pragma unroll
            for (int g = 0; g < 4; ++g)
                Ps[(size_t)(q0 + r * 16 + quad * 4 + g) * DIM + wd + c * 16 + col]
                    = f2bf(accO[r][c][g]);
}

// ---------------------------------------------------------------------------
// Finalize: T = (P0+P1)/(l0+l1) (bf16 partials), out = T @ Wv^T + bv.
// 256 blocks x 512 thr, 32 rows/block.
// ---------------------------------------------------------------------------
__global__ __launch_bounds__(512)
void finalize_kernel(const int* __restrict__ flag,
                     const ushort_t* __restrict__ P0, const ushort_t* __restrict__ P1,
                     const float* __restrict__ lsumA,
                     const void* __restrict__ Wv, const void* __restrict__ bv,
                     void* __restrict__ Out)
{
    __shared__ ushort_t Alds[32][LDA];
    const bool f32 = (*flag == 0);
    const int tid  = threadIdx.x;
    const int wave = tid >> 6;
    const int lane = tid & 63;
    const int quad = lane >> 4;
    const int col  = lane & 15;
    const int mblk = blockIdx.x * 32;

    #pragma unroll
    for (int i = 0; i < 4; ++i) {
        int chunk = i * 512 + tid;
        int row = chunk >> 6;
        int k8  = (chunk & 63) * 8;
        int m   = mblk + row;
        float rv = 1.0f / (lsumA[m] + lsumA[NTOK + m]);
        bf16x8 v0 = *(const bf16x8*)&P0[(size_t)m * 512 + k8];
        bf16x8 v1 = *(const bf16x8*)&P1[(size_t)m * 512 + k8];
        bf16x8 t;
        #pragma unroll
        for (int j = 0; j < 8; ++j) t[j] = f2bfh(((float)v0[j] + (float)v1[j]) * rv);
        *(bf16x8*)&Alds[row][k8] = t;
    }
    __syncthreads();

    f32x4 acc[2][4];
    #pragma unroll
    for (int r = 0; r < 2; ++r)
        #pragma unroll
        for (int c = 0; c < 4; ++c) acc[r][c] = (f32x4){0.f, 0.f, 0.f, 0.f};

    const int wcol = wave * 64;
    #pragma unroll
    for (int kk = 0; kk < 16; ++kk) {
        bf16x8 a0 = *(const bf16x8*)&Alds[col][kk * 32 + quad * 8];
        bf16x8 a1 = *(const bf16x8*)&Alds[16 + col][kk * 32 + quad * 8];
        #pragma unroll
        for (int c = 0; c < 4; ++c) {
            bf16x8 b = load8(Wv, (size_t)(wcol + c * 16 + col) * 512 + kk * 32 + quad * 8, f32);
            acc[0][c] = mfma16(a0, b, acc[0][c]);
            acc[1][c] = mfma16(a1, b, acc[1][c]);
        }
    }

    #pragma unroll
    for (int r = 0; r < 2; ++r)
        #pragma unroll
        for (int c = 0; c < 4; ++c)
            #pragma unroll
            for (int g = 0; g < 4; ++g) {
                int m = mblk + r * 16 + quad * 4 + g;
                int n = wcol + c * 16 + col;
                float v = acc[r][c][g] + loadS(bv, n, f32);
                if (f32) ((float*)Out)[(size_t)m * DIM + n] = v;
                else     ((ushort_t*)Out)[(size_t)m * DIM + n] = f2bf(v);
            }
}

// ---------------------------------------------------------------------------
// Fallback fused attention (R6-proven) for smaller workspaces.
// ---------------------------------------------------------------------------
template <int VT>
__global__ __launch_bounds__(1024)
void attn_fused_kernel(const int* __restrict__ flag, const ushort_t* __restrict__ Q,
                       const void* __restrict__ embOrT, const void* __restrict__ Wv,
                       const void* __restrict__ bv, void* __restrict__ Out)
{
    __shared__ ushort_t Qlds[32][LDA];
    __shared__ ushort_t Plds[2][32][LDP];
    __shared__ float    Lpart[16][32];

    const bool f32 = (*flag == 0);
    const int tid  = threadIdx.x;
    const int wave = tid >> 6;
    const int lane = tid & 63;
    const int quad = lane >> 4;
    const int col  = lane & 15;
    const int q0   = blockIdx.x * 32;

    #pragma unroll
    for (int i = 0; i < 2; ++i) {
        int chunk = i * 1024 + tid;
        int row = chunk >> 6;
        int k8  = (chunk & 63) * 8;
        *(bf16x8*)&Qlds[row][k8] = *(const bf16x8*)&Q[(size_t)(q0 + row) * 512 + k8];
    }
    __syncthreads();

    f32x4 accO[2][2];
    #pragma unroll
    for (int r = 0; r < 2; ++r)
        #pragma unroll
        for (int c = 0; c < 2; ++c) accO[r][c] = (f32x4){0.f, 0.f, 0.f, 0.f};

    float lsum[2][4];
    #pragma unroll
    for (int r = 0; r < 2; ++r)
        #pragma unroll
        for (int g = 0; g < 4; ++g) lsum[r][g] = 0.f;

    const float sc = 0.04419417382415922f * 1.4426950408889634f;
    const int wOcol = wave * 32;

    for (int it = 0; it < 32; ++it) {
        const int j0  = it * 256;
        const int buf = it & 1;

        bf16x8 kb[16];
        const size_t keyrow = (size_t)(j0 + wave * 16 + col) * 512;
        #pragma unroll
        for (int kk = 0; kk < 16; ++kk)
            kb[kk] = *(const bf16x8*)&Q[keyrow + kk * 32 + quad * 8];

        f32x4 accS[2];
        accS[0] = (f32x4){0.f, 0.f, 0.f, 0.f};
        accS[1] = (f32x4){0.f, 0.f, 0.f, 0.f};
        #pragma unroll
        for (int kk = 0; kk < 16; ++kk) {
            bf16x8 a0 = *(const bf16x8*)&Qlds[col][kk * 32 + quad * 8];
            bf16x8 a1 = *(const bf16x8*)&Qlds[16 + col][kk * 32 + quad * 8];
            accS[0] = mfma16(a0, kb[kk], accS[0]);
            accS[1] = mfma16(a1, kb[kk], accS[1]);
        }

        bf16x8 vb[16];
        #pragma unroll
        for (int kk = 0; kk < 8; ++kk)
            #pragma unroll
            for (int c = 0; c < 2; ++c) {
                if (VT) {
                    vb[kk * 2 + c] = *(const bf16x8*)((const ushort_t*)embOrT
                        + (size_t)(wOcol + c * 16 + col) * NTOK + j0 + kk * 32 + quad * 8);
                } else {
                    size_t base = (size_t)(j0 + kk * 32 + quad * 8) * 512 + (wOcol + c * 16 + col);
                    bf16x8 b;
                    if (f32) {
                        const float* bp = (const float*)embOrT + base;
                        #pragma unroll
                        for (int j = 0; j < 8; ++j) b[j] = f2bfh(bp[(size_t)j * 512]);
                    } else {
                        const __bf16* bp = (const __bf16*)embOrT + base;
                        #pragma unroll
                        for (int j = 0; j < 8; ++j) b[j] = bp[(size_t)j * 512];
                    }
                    vb[kk * 2 + c] = b;
                }
            }

        #pragma unroll
        for (int r = 0; r < 2; ++r)
            #pragma unroll
            for (int g = 0; g < 4; ++g) {
                float p = exp2f(fminf(accS[r][g] * sc, 126.0f));
                lsum[r][g] += p;
                Plds[buf][r * 16 + quad * 4 + g][wave * 16 + col] = f2bf(p);
            }

        __syncthreads();

        #pragma unroll
        for (int kk = 0; kk < 8; ++kk) {
            bf16x8 a0 = *(const bf16x8*)&Plds[buf][col][kk * 32 + quad * 8];
            bf16x8 a1 = *(const bf16x8*)&Plds[buf][16 + col][kk * 32 + quad * 8];
            #pragma unroll
            for (int c = 0; c < 2; ++c) {
                accO[0][c] = mfma16(a0, vb[kk * 2 + c], accO[0][c]);
                accO[1][c] = mfma16(a1, vb[kk * 2 + c], accO[1][c]);
            }
        }
    }

    #pragma unroll
    for (int r = 0; r < 2; ++r)
        #pragma unroll
        for (int g = 0; g < 4; ++g) {
            float s = lsum[r][g];
            s += __shfl_xor(s, 1);
            s += __shfl_xor(s, 2);
            s += __shfl_xor(s, 4);
            s += __shfl_xor(s, 8);
            lsum[r][g] = s;
        }
    if (col == 0) {
        #pragma unroll
        for (int r = 0; r < 2; ++r)
            #pragma unroll
            for (int g = 0; g < 4; ++g)
                Lpart[wave][r * 16 + quad * 4 + g] = lsum[r][g];
    }
    __syncthreads();

    #pragma unroll
    for (int r = 0; r < 2; ++r) {
        float rinv[4];
        #pragma unroll
        for (int g = 0; g < 4; ++g) {
            float t = 0.f;
            #pragma unroll
            for (int w = 0; w < 16; ++w) t += Lpart[w][r * 16 + quad * 4 + g];
            rinv[g] = 1.0f / t;
        }
        #pragma unroll
        for (int c = 0; c < 2; ++c)
            #pragma unroll
            for (int g = 0; g < 4; ++g)
                Qlds[r * 16 + quad * 4 + g][wOcol + c * 16 + col] = f2bf(accO[r][c][g] * rinv[g]);
    }
    __syncthreads();

    f32x4 acc2[2][2];
    #pragma unroll
    for (int r = 0; r < 2; ++r)
        #pragma unroll
        for (int c = 0; c < 2; ++c) acc2[r][c] = (f32x4){0.f, 0.f, 0.f, 0.f};

    #pragma unroll
    for (int kk = 0; kk < 16; ++kk) {
        bf16x8 a0 = *(const bf16x8*)&Qlds[col][kk * 32 + quad * 8];
        bf16x8 a1 = *(const bf16x8*)&Qlds[16 + col][kk * 32 + quad * 8];
        #pragma unroll
        for (int c = 0; c < 2; ++c) {
            bf16x8 b = load8(Wv, (size_t)(wOcol + c * 16 + col) * 512 + kk * 32 + quad * 8, f32);
            acc2[0][c] = mfma16(a0, b, acc2[0][c]);
            acc2[1][c] = mfma16(a1, b, acc2[1][c]);
        }
    }

    #pragma unroll
    for (int r = 0; r < 2; ++r)
        #pragma unroll
        for (int c = 0; c < 2; ++c)
            #pragma unroll
            for (int g = 0; g < 4; ++g) {
                int m = q0 + r * 16 + quad * 4 + g;
                int n = wOcol + c * 16 + col;
                float v = acc2[r][c][g] + loadS(bv, n, f32);
                if (f32) ((float*)Out)[(size_t)m * DIM + n] = v;
                else     ((ushort_t*)Out)[(size_t)m * DIM + n] = f2bf(v);
            }
}

extern "C" void kernel_launch(void* const* d_in, const int* in_sizes, int n_in,
                              void* d_out, int out_size, void* d_ws, size_t ws_size,
                              hipStream_t stream)
{
    const void* emb = d_in[0];
    const void* Wqk = d_in[1];
    const void* bqk = d_in[2];
    const void* Wv  = d_in[3];
    const void* bv  = d_in[4];

    char* W = (char*)d_ws;
    int*      flag  = (int*)W;
    float*    lsumA = (float*)(W + 64);                        // 2x8192 fp32 = 64 KB
    ushort_t* embT  = (ushort_t*)(W + 64 + 65536);             // 8 MB
    ushort_t* Qws   = embT + (size_t)DIM * NTOK;               // 8 MB
    ushort_t* P0    = Qws + (size_t)DIM * NTOK;                // 8 MB bf16 partial
    ushort_t* P1    = P0 + (size_t)NTOK * DIM;                 // 8 MB bf16 partial

    const size_t needA = 64 + 65536 + 4 * (size_t)NTOK * DIM * 2;   // ~32.1 MB
    const size_t needB = 64 + 2 * (size_t)NTOK * DIM * 2;           // 16.03 MB

    detect_kernel<<<dim3(1), dim3(64), 0, stream>>>((const ushort_t*)emb, flag);

    if (ws_size >= needA) {
        transpose_kernel<<<dim3(128, 8), dim3(256), 0, stream>>>(flag, emb, embT);
        projq_kernel<<<dim3(NTOK / 32), dim3(512), 0, stream>>>(flag, emb, Wqk, bqk, Qws);
        attn64_kernel<<<dim3(256), dim3(1024), 0, stream>>>(Qws, embT, P0, P1, lsumA);
        finalize_kernel<<<dim3(NTOK / 32), dim3(512), 0, stream>>>(flag, P0, P1, lsumA,
                                                                   Wv, bv, d_out);
    } else if (ws_size >= needB) {
        ushort_t* embT2 = (ushort_t*)(W + 64);
        ushort_t* Qws2  = embT2 + (size_t)DIM * NTOK;
        transpose_kernel<<<dim3(128, 8), dim3(256), 0, stream>>>(flag, emb, embT2);
        projq_kernel<<<dim3(NTOK / 32), dim3(512), 0, stream>>>(flag, emb, Wqk, bqk, Qws2);
        attn_fused_kernel<1><<<dim3(NTOK / 32), dim3(1024), 0, stream>>>(
            flag, Qws2, embT2, Wv, bv, d_out);
    } else {
        ushort_t* Qsm = (ushort_t*)(W + 64);
        projq_kernel<<<dim3(NTOK / 32), dim3(512), 0, stream>>>(flag, emb, Wqk, bqk, Qsm);
        attn_fused_kernel<0><<<dim3(NTOK / 32), dim3(1024), 0, stream>>>(
            flag, Qsm, emb, Wv, bv, d_out);
    }
}

// Round 14
// 382.626 us; speedup vs baseline: 1.5739x; 1.0749x over previous
//
#include <hip/hip_runtime.h>
#include <hip/hip_bf16.h>

// N=8192, D=512.  Q = emb@Wqk^T+bqk (K==Q); out = softmax(QK^T/sqrt(512)) @ V.
// Softmax rows sum to 1 => out = (softmax(S)@emb) @ Wv^T + bv (V never built).
// Device dtype runtime-detected (fp32 observed). Internal: bf16 MFMA, fp32 acc.
// R13 post-mortem: attn64 (285us) is within 5% of the measured ~7.5 TB/s
// cache-fabric traffic floor (2.05 GB). R14 harvests the 126us of satellites:
// prep converts weights to bf16 once; projqT64 fuses emb-transpose into the
// Q-projection (64-row tiles, no separate transpose launch/emb re-read);
// finalize64 uses 64-row tiles + bf16 Wv (weight re-read 256->64 MB).
// attn64 unchanged (R13-proven, spill-free).

#define NTOK 8192
#define DIM  512

typedef unsigned short ushort_t;
typedef __attribute__((ext_vector_type(8))) __bf16 bf16x8;
typedef __attribute__((ext_vector_type(4))) float f32x4;

__device__ __forceinline__ float bf2f(ushort_t u) {
    union { unsigned int i; float f; } v; v.i = ((unsigned int)u) << 16; return v.f;
}
__device__ __forceinline__ ushort_t f2bf(float f) {
    union { float f; unsigned int i; } v; v.f = f;
    unsigned int b = v.i;
    return (ushort_t)((b + 0x7FFFu + ((b >> 16) & 1u)) >> 16);   // RNE
}
__device__ __forceinline__ __bf16 f2bfh(float f) {
    union { ushort_t u; __bf16 h; } c; c.u = f2bf(f); return c.h;
}
__device__ __forceinline__ f32x4 mfma16(bf16x8 a, bf16x8 b, f32x4 c) {
    return __builtin_amdgcn_mfma_f32_16x16x32_bf16(a, b, c, 0, 0, 0);
}
__device__ __forceinline__ bf16x8 load8(const void* p, size_t idx, bool f32) {
    if (f32) {
        const float* f = (const float*)p + idx;
        bf16x8 r;
        #pragma unroll
        for (int j = 0; j < 8; ++j) r[j] = f2bfh(f[j]);
        return r;
    }
    return *(const bf16x8*)((const ushort_t*)p + idx);
}
__device__ __forceinline__ float loadS(const void* p, size_t idx, bool f32) {
    return f32 ? ((const float*)p)[idx] : bf2f(((const ushort_t*)p)[idx]);
}

#define LDA 520   // 260 dw, %32=4: uniform 2 dw/bank for b128 row reads
#define LDP 264

// ---------------------------------------------------------------------------
// Dtype probe: flag=1 => bf16 data, flag=0 => fp32.
// ---------------------------------------------------------------------------
__global__ void detect_kernel(const ushort_t* __restrict__ emb, int* __restrict__ flag)
{
    int lane = threadIdx.x;
    int cnt = 0;
    #pragma unroll
    for (int i = 0; i < 8; ++i) {
        ushort_t u = emb[(size_t)(lane * 8 + i) * 2];
        int a = u & 0x7FFF;
        int e = (u >> 7) & 0xFF;
        if (a == 0 || (e >= 111 && e <= 143)) cnt++;
    }
    cnt += __shfl_xor(cnt, 1);  cnt += __shfl_xor(cnt, 2);  cnt += __shfl_xor(cnt, 4);
    cnt += __shfl_xor(cnt, 8);  cnt += __shfl_xor(cnt, 16); cnt += __shfl_xor(cnt, 32);
    if (lane == 0) *flag = (cnt >= 460) ? 1 : 0;
}

// ---------------------------------------------------------------------------
// Prep: convert Wqk, Wv (512x512) + bqk, bv (512) to bf16 in ws.
// 128 blocks x 256 thr, 8 elems each per weight.
// ---------------------------------------------------------------------------
__global__ __launch_bounds__(256)
void prep_kernel(const int* __restrict__ flag,
                 const void* __restrict__ Wqk, const void* __restrict__ bqk,
                 const void* __restrict__ Wv,  const void* __restrict__ bv,
                 ushort_t* __restrict__ Wqkb, ushort_t* __restrict__ bqkb,
                 ushort_t* __restrict__ Wvb,  ushort_t* __restrict__ bvb)
{
    const bool f32 = (*flag == 0);
    size_t gid = (size_t)blockIdx.x * 256 + threadIdx.x;   // 32768 threads
    size_t base = gid * 8;                                  // 262144 = 512*512
    *(bf16x8*)&Wqkb[base] = load8(Wqk, base, f32);
    *(bf16x8*)&Wvb[base]  = load8(Wv,  base, f32);
    if (gid < 64) {
        *(bf16x8*)&bqkb[base] = load8(bqk, base, f32);
        *(bf16x8*)&bvb[base]  = load8(bv,  base, f32);
    }
}

// ---------------------------------------------------------------------------
// Fused: Q[64 rows] = emb@Wqk^T+bqk AND embT columns, from one staged tile.
// 128 blocks x 512 thr (8 waves); wave w owns out cols [64w,64w+64).
// ---------------------------------------------------------------------------
__global__ __launch_bounds__(512)
void projqT_kernel(const int* __restrict__ flag, const void* __restrict__ emb,
                   const ushort_t* __restrict__ Wb, const ushort_t* __restrict__ bb,
                   ushort_t* __restrict__ C, ushort_t* __restrict__ embT)
{
    __shared__ ushort_t Alds[64][LDA];   // 66,560 B
    const bool f32 = (*flag == 0);
    const int tid  = threadIdx.x;
    const int wave = tid >> 6;
    const int lane = tid & 63;
    const int quad = lane >> 4;
    const int col  = lane & 15;
    const int mblk = blockIdx.x * 64;

    #pragma unroll
    for (int i = 0; i < 8; ++i) {
        int chunk = i * 512 + tid;
        int row = chunk >> 6;
        int k8  = (chunk & 63) * 8;
        *(bf16x8*)&Alds[row][k8] = load8(emb, (size_t)(mblk + row) * 512 + k8, f32);
    }
    __syncthreads();

    // ---- transpose store: thread t owns dim t, 64 tokens (128 B) ----
    {
        ushort_t buf[64];
        #pragma unroll
        for (int r = 0; r < 64; ++r) buf[r] = Alds[r][tid];
        ushort_t* dst = embT + (size_t)tid * NTOK + mblk;
        #pragma unroll
        for (int i = 0; i < 8; ++i)
            *(uint4*)(dst + i * 8) = *(uint4*)&buf[i * 8];
    }

    // ---- Q projection (64 rows x this wave's 64 cols) ----
    f32x4 acc[4][4];
    #pragma unroll
    for (int r = 0; r < 4; ++r)
        #pragma unroll
        for (int c = 0; c < 4; ++c) acc[r][c] = (f32x4){0.f, 0.f, 0.f, 0.f};

    const int wcol = wave * 64;
    #pragma unroll
    for (int kk = 0; kk < 16; ++kk) {
        bf16x8 a[4];
        #pragma unroll
        for (int r = 0; r < 4; ++r)
            a[r] = *(const bf16x8*)&Alds[r * 16 + col][kk * 32 + quad * 8];
        #pragma unroll
        for (int c = 0; c < 4; ++c) {
            bf16x8 b = *(const bf16x8*)&Wb[(size_t)(wcol + c * 16 + col) * 512
                                           + kk * 32 + quad * 8];
            #pragma unroll
            for (int r = 0; r < 4; ++r)
                acc[r][c] = mfma16(a[r], b, acc[r][c]);
        }
    }

    #pragma unroll
    for (int r = 0; r < 4; ++r)
        #pragma unroll
        for (int c = 0; c < 4; ++c)
            #pragma unroll
            for (int g = 0; g < 4; ++g) {
                int m = mblk + r * 16 + quad * 4 + g;
                int n = wcol + c * 16 + col;
                C[(size_t)m * DIM + n] = f2bf(acc[r][c][g] + bf2f(bb[n]));
            }
}

// ---------------------------------------------------------------------------
// Attention partials (R13-proven, unchanged): 256 blocks = 128 q-tiles (Tq=64)
// x 2 key-halves, 1024 thr = 16 waves, KT=256 (16 iters), dbuf Plds.
// ---------------------------------------------------------------------------
__global__ __launch_bounds__(1024)
void attn64_kernel(const ushort_t* __restrict__ Q, const ushort_t* __restrict__ embT,
                   ushort_t* __restrict__ P0, ushort_t* __restrict__ P1,
                   float* __restrict__ lsumA)
{
    __shared__ ushort_t Qlds[64][LDA];
    __shared__ ushort_t Plds[2][64][LDP];
    __shared__ float    Lp[16][64];

    const int tid  = threadIdx.x;
    const int wave = tid >> 6;
    const int lane = tid & 63;
    const int quad = lane >> 4;
    const int col  = lane & 15;
    const int qt   = blockIdx.x & 127;
    const int ks   = blockIdx.x >> 7;
    const int q0   = qt * 64;
    const int kbase = ks * 4096;
    ushort_t* Ps = ks ? P1 : P0;

    #pragma unroll
    for (int i = 0; i < 4; ++i) {
        int chunk = i * 1024 + tid;
        int row = chunk >> 6;
        int k8  = (chunk & 63) * 8;
        *(bf16x8*)&Qlds[row][k8] = *(const bf16x8*)&Q[(size_t)(q0 + row) * 512 + k8];
    }
    __syncthreads();

    f32x4 accO[4][2];
    #pragma unroll
    for (int r = 0; r < 4; ++r)
        #pragma unroll
        for (int c = 0; c < 2; ++c) accO[r][c] = (f32x4){0.f, 0.f, 0.f, 0.f};

    float lsum[4][4];
    #pragma unroll
    for (int r = 0; r < 4; ++r)
        #pragma unroll
        for (int g = 0; g < 4; ++g) lsum[r][g] = 0.f;

    const float sc = 0.04419417382415922f * 1.4426950408889634f;  // 1/sqrt(512)*log2e
    const int wd = wave * 32;

    for (int it = 0; it < 16; ++it) {
        const int j0  = kbase + it * 256;
        const int buf = it & 1;

        f32x4 accS[4];
        #pragma unroll
        for (int r = 0; r < 4; ++r) accS[r] = (f32x4){0.f, 0.f, 0.f, 0.f};
        const size_t keyrow = (size_t)(j0 + wave * 16 + col) * 512;
        #pragma unroll
        for (int h = 0; h < 2; ++h) {
            bf16x8 kb[8];
            #pragma unroll
            for (int kk = 0; kk < 8; ++kk)
                kb[kk] = *(const bf16x8*)&Q[keyrow + (h * 8 + kk) * 32 + quad * 8];
            #pragma unroll
            for (int kk = 0; kk < 8; ++kk) {
                const int cofs = (h * 8 + kk) * 32 + quad * 8;
                #pragma unroll
                for (int r = 0; r < 4; ++r) {
                    bf16x8 a = *(const bf16x8*)&Qlds[r * 16 + col][cofs];
                    accS[r] = mfma16(a, kb[kk], accS[r]);
                }
            }
        }

        bf16x8 vbA[8];
        #pragma unroll
        for (int kk = 0; kk < 4; ++kk)
            #pragma unroll
            for (int c = 0; c < 2; ++c)
                vbA[kk * 2 + c] = *(const bf16x8*)&embT[
                    (size_t)(wd + c * 16 + col) * NTOK + j0 + kk * 32 + quad * 8];

        #pragma unroll
        for (int r = 0; r < 4; ++r)
            #pragma unroll
            for (int g = 0; g < 4; ++g) {
                float p = exp2f(fminf(accS[r][g] * sc, 126.0f));
                lsum[r][g] += p;
                Plds[buf][r * 16 + quad * 4 + g][wave * 16 + col] = f2bf(p);
            }

        bf16x8 vbB[8];
        #pragma unroll
        for (int kk = 0; kk < 4; ++kk)
            #pragma unroll
            for (int c = 0; c < 2; ++c)
                vbB[kk * 2 + c] = *(const bf16x8*)&embT[
                    (size_t)(wd + c * 16 + col) * NTOK + j0 + (4 + kk) * 32 + quad * 8];

        __syncthreads();   // P(t) visible; buf reuse at distance 2 safe

        #pragma unroll
        for (int kk = 0; kk < 4; ++kk) {
            #pragma unroll
            for (int r = 0; r < 4; ++r) {
                bf16x8 a = *(const bf16x8*)&Plds[buf][r * 16 + col][kk * 32 + quad * 8];
                #pragma unroll
                for (int c = 0; c < 2; ++c)
                    accO[r][c] = mfma16(a, vbA[kk * 2 + c], accO[r][c]);
            }
        }
        #pragma unroll
        for (int kk = 0; kk < 4; ++kk) {
            #pragma unroll
            for (int r = 0; r < 4; ++r) {
                bf16x8 a = *(const bf16x8*)&Plds[buf][r * 16 + col][(4 + kk) * 32 + quad * 8];
                #pragma unroll
                for (int c = 0; c < 2; ++c)
                    accO[r][c] = mfma16(a, vbB[kk * 2 + c], accO[r][c]);
            }
        }
    }

    #pragma unroll
    for (int r = 0; r < 4; ++r)
        #pragma unroll
        for (int g = 0; g < 4; ++g) {
            float s = lsum[r][g];
            s += __shfl_xor(s, 1);
            s += __shfl_xor(s, 2);
            s += __shfl_xor(s, 4);
            s += __shfl_xor(s, 8);
            if (col == 0)
                Lp[wave][r * 16 + quad * 4 + g] = s;
        }
    __syncthreads();
    if (tid < 64) {
        float t = 0.f;
        #pragma unroll
        for (int w = 0; w < 16; ++w) t += Lp[w][tid];
        lsumA[(size_t)ks * NTOK + q0 + tid] = t;
    }

    #pragma unroll
    for (int r = 0; r < 4; ++r)
        #pragma unroll
        for (int c = 0; c < 2; ++c)
            #pragma unroll
            for (int g = 0; g < 4; ++g)
                Ps[(size_t)(q0 + r * 16 + quad * 4 + g) * DIM + wd + c * 16 + col]
                    = f2bf(accO[r][c][g]);
}

// ---------------------------------------------------------------------------
// Finalize64: T = (P0+P1)/(l0+l1), out = T @ Wv^T + bv (bf16 weights).
// 128 blocks x 512 thr, 64 rows/block.
// ---------------------------------------------------------------------------
__global__ __launch_bounds__(512)
void finalize_kernel(const int* __restrict__ flag,
                     const ushort_t* __restrict__ P0, const ushort_t* __restrict__ P1,
                     const float* __restrict__ lsumA,
                     const ushort_t* __restrict__ Wb, const ushort_t* __restrict__ bb,
                     void* __restrict__ Out)
{
    __shared__ ushort_t Alds[64][LDA];
    const bool f32 = (*flag == 0);
    const int tid  = threadIdx.x;
    const int wave = tid >> 6;
    const int lane = tid & 63;
    const int quad = lane >> 4;
    const int col  = lane & 15;
    const int mblk = blockIdx.x * 64;

    #pragma unroll
    for (int i = 0; i < 8; ++i) {
        int chunk = i * 512 + tid;
        int row = chunk >> 6;
        int k8  = (chunk & 63) * 8;
        int m   = mblk + row;
        float rv = 1.0f / (lsumA[m] + lsumA[NTOK + m]);
        bf16x8 v0 = *(const bf16x8*)&P0[(size_t)m * 512 + k8];
        bf16x8 v1 = *(const bf16x8*)&P1[(size_t)m * 512 + k8];
        bf16x8 t;
        #pragma unroll
        for (int j = 0; j < 8; ++j) t[j] = f2bfh(((float)v0[j] + (float)v1[j]) * rv);
        *(bf16x8*)&Alds[row][k8] = t;
    }
    __syncthreads();

    f32x4 acc[4][4];
    #pragma unroll
    for (int r = 0; r < 4; ++r)
        #pragma unroll
        for (int c = 0; c < 4; ++c) acc[r][c] = (f32x4){0.f, 0.f, 0.f, 0.f};

    const int wcol = wave * 64;
    #pragma unroll
    for (int kk = 0; kk < 16; ++kk) {
        bf16x8 a[4];
        #pragma unroll
        for (int r = 0; r < 4; ++r)
            a[r] = *(const bf16x8*)&Alds[r * 16 + col][kk * 32 + quad * 8];
        #pragma unroll
        for (int c = 0; c < 4; ++c) {
            bf16x8 b = *(const bf16x8*)&Wb[(size_t)(wcol + c * 16 + col) * 512
                                           + kk * 32 + quad * 8];
            #pragma unroll
            for (int r = 0; r < 4; ++r)
                acc[r][c] = mfma16(a[r], b, acc[r][c]);
        }
    }

    #pragma unroll
    for (int r = 0; r < 4; ++r)
        #pragma unroll
        for (int c = 0; c < 4; ++c)
            #pragma unroll
            for (int g = 0; g < 4; ++g) {
                int m = mblk + r * 16 + quad * 4 + g;
                int n = wcol + c * 16 + col;
                float v = acc[r][c][g] + bf2f(bb[n]);
                if (f32) ((float*)Out)[(size_t)m * DIM + n] = v;
                else     ((ushort_t*)Out)[(size_t)m * DIM + n] = f2bf(v);
            }
}

// ---------------------------------------------------------------------------
// Fallback kernels (R13-proven) for smaller workspaces.
// ---------------------------------------------------------------------------
__global__ __launch_bounds__(256)
void transpose_kernel(const int* __restrict__ flag, const void* __restrict__ emb,
                      ushort_t* __restrict__ embT)
{
    __shared__ float tile[64][65];
    const bool f32 = (*flag == 0);
    const int t  = threadIdx.x;
    const int j0 = blockIdx.x * 64;
    const int d0 = blockIdx.y * 64;
    {
        int r = t >> 2, cs = (t & 3) * 16;
        if (f32) {
            const float* src = (const float*)emb + (size_t)(j0 + r) * DIM + d0 + cs;
            #pragma unroll
            for (int i = 0; i < 16; i += 4) {
                float4 v = *(const float4*)(src + i);
                tile[r][cs + i]     = v.x;
                tile[r][cs + i + 1] = v.y;
                tile[r][cs + i + 2] = v.z;
                tile[r][cs + i + 3] = v.w;
            }
        } else {
            const ushort_t* src = (const ushort_t*)emb + (size_t)(j0 + r) * DIM + d0 + cs;
            #pragma unroll
            for (int i = 0; i < 16; ++i) tile[r][cs + i] = bf2f(src[i]);
        }
    }
    __syncthreads();
    {
        int d = t >> 2, js = (t & 3) * 16;
        ushort_t buf[16];
        #pragma unroll
        for (int i = 0; i < 16; ++i) buf[i] = f2bf(tile[js + i][d]);
        ushort_t* dst = embT + (size_t)(d0 + d) * NTOK + j0 + js;
        *(uint4*)dst       = *(uint4*)&buf[0];
        *(uint4*)(dst + 8) = *(uint4*)&buf[8];
    }
}

__global__ __launch_bounds__(512)
void projq_kernel(const int* __restrict__ flag, const void* __restrict__ emb,
                  const void* __restrict__ W, const void* __restrict__ bias,
                  ushort_t* __restrict__ C)
{
    __shared__ ushort_t Alds[32][LDA];
    const bool f32 = (*flag == 0);
    const int tid  = threadIdx.x;
    const int wave = tid >> 6;
    const int lane = tid & 63;
    const int quad = lane >> 4;
    const int col  = lane & 15;
    const int mblk = blockIdx.x * 32;

    #pragma unroll
    for (int i = 0; i < 4; ++i) {
        int chunk = i * 512 + tid;
        int row = chunk >> 6;
        int k8  = (chunk & 63) * 8;
        *(bf16x8*)&Alds[row][k8] = load8(emb, (size_t)(mblk + row) * 512 + k8, f32);
    }
    __syncthreads();

    f32x4 acc[2][4];
    #pragma unroll
    for (int r = 0; r < 2; ++r)
        #pragma unroll
        for (int c = 0; c < 4; ++c) acc[r][c] = (f32x4){0.f, 0.f, 0.f, 0.f};

    const int wcol = wave * 64;
    #pragma unroll
    for (int kk = 0; kk < 16; ++kk) {
        bf16x8 a0 = *(const bf16x8*)&Alds[col][kk * 32 + quad * 8];
        bf16x8 a1 = *(const bf16x8*)&Alds[16 + col][kk * 32 + quad * 8];
        #pragma unroll
        for (int c = 0; c < 4; ++c) {
            bf16x8 b = load8(W, (size_t)(wcol + c * 16 + col) * 512 + kk * 32 + quad * 8, f32);
            acc[0][c] = mfma16(a0, b, acc[0][c]);
            acc[1][c] = mfma16(a1, b, acc[1][c]);
        }
    }

    #pragma unroll
    for (int r = 0; r < 2; ++r)
        #pragma unroll
        for (int c = 0; c < 4; ++c)
            #pragma unroll
            for (int g = 0; g < 4; ++g) {
                int m = mblk + r * 16 + quad * 4 + g;
                int n = wcol + c * 16 + col;
                C[(size_t)m * DIM + n] = f2bf(acc[r][c][g] + loadS(bias, n, f32));
            }
}

template <int VT>
__global__ __launch_bounds__(1024)
void attn_fused_kernel(const int* __restrict__ flag, const ushort_t* __restrict__ Q,
                       const void* __restrict__ embOrT, const void* __restrict__ Wv,
                       const void* __restrict__ bv, void* __restrict__ Out)
{
    __shared__ ushort_t Qlds[32][LDA];
    __shared__ ushort_t Plds[2][32][LDP];
    __shared__ float    Lpart[16][32];

    const bool f32 = (*flag == 0);
    const int tid  = threadIdx.x;
    const int wave = tid >> 6;
    const int lane = tid & 63;
    const int quad = lane >> 4;
    const int col  = lane & 15;
    const int q0   = blockIdx.x * 32;

    #pragma unroll
    for (int i = 0; i < 2; ++i) {
        int chunk = i * 1024 + tid;
        int row = chunk >> 6;
        int k8  = (chunk & 63) * 8;
        *(bf16x8*)&Qlds[row][k8] = *(const bf16x8*)&Q[(size_t)(q0 + row) * 512 + k8];
    }
    __syncthreads();

    f32x4 accO[2][2];
    #pragma unroll
    for (int r = 0; r < 2; ++r)
        #pragma unroll
        for (int c = 0; c < 2; ++c) accO[r][c] = (f32x4){0.f, 0.f, 0.f, 0.f};

    float lsum[2][4];
    #pragma unroll
    for (int r = 0; r < 2; ++r)
        #pragma unroll
        for (int g = 0; g < 4; ++g) lsum[r][g] = 0.f;

    const float sc = 0.04419417382415922f * 1.4426950408889634f;
    const int wOcol = wave * 32;

    for (int it = 0; it < 32; ++it) {
        const int j0  = it * 256;
        const int buf = it & 1;

        bf16x8 kb[16];
        const size_t keyrow = (size_t)(j0 + wave * 16 + col) * 512;
        #pragma unroll
        for (int kk = 0; kk < 16; ++kk)
            kb[kk] = *(const bf16x8*)&Q[keyrow + kk * 32 + quad * 8];

        f32x4 accS[2];
        accS[0] = (f32x4){0.f, 0.f, 0.f, 0.f};
        accS[1] = (f32x4){0.f, 0.f, 0.f, 0.f};
        #pragma unroll
        for (int kk = 0; kk < 16; ++kk) {
            bf16x8 a0 = *(const bf16x8*)&Qlds[col][kk * 32 + quad * 8];
            bf16x8 a1 = *(const bf16x8*)&Qlds[16 + col][kk * 32 + quad * 8];
            accS[0] = mfma16(a0, kb[kk], accS[0]);
            accS[1] = mfma16(a1, kb[kk], accS[1]);
        }

        bf16x8 vb[16];
        #pragma unroll
        for (int kk = 0; kk < 8; ++kk)
            #pragma unroll
            for (int c = 0; c < 2; ++c) {
                if (VT) {
                    vb[kk * 2 + c] = *(const bf16x8*)((const ushort_t*)embOrT
                        + (size_t)(wOcol + c * 16 + col) * NTOK + j0 + kk * 32 + quad * 8);
                } else {
                    size_t base = (size_t)(j0 + kk * 32 + quad * 8) * 512 + (wOcol + c * 16 + col);
                    bf16x8 b;
                    if (f32) {
                        const float* bp = (const float*)embOrT + base;
                        #pragma unroll
                        for (int j = 0; j < 8; ++j) b[j] = f2bfh(bp[(size_t)j * 512]);
                    } else {
                        const __bf16* bp = (const __bf16*)embOrT + base;
                        #pragma unroll
                        for (int j = 0; j < 8; ++j) b[j] = bp[(size_t)j * 512];
                    }
                    vb[kk * 2 + c] = b;
                }
            }

        #pragma unroll
        for (int r = 0; r < 2; ++r)
            #pragma unroll
            for (int g = 0; g < 4; ++g) {
                float p = exp2f(fminf(accS[r][g] * sc, 126.0f));
                lsum[r][g] += p;
                Plds[buf][r * 16 + quad * 4 + g][wave * 16 + col] = f2bf(p);
            }

        __syncthreads();

        #pragma unroll
        for (int kk = 0; kk < 8; ++kk) {
            bf16x8 a0 = *(const bf16x8*)&Plds[buf][col][kk * 32 + quad * 8];
            bf16x8 a1 = *(const bf16x8*)&Plds[buf][16 + col][kk * 32 + quad * 8];
            #pragma unroll
            for (int c = 0; c < 2; ++c) {
                accO[0][c] = mfma16(a0, vb[kk * 2 + c], accO[0][c]);
                accO[1][c] = mfma16(a1, vb[kk * 2 + c], accO[1][c]);
            }
        }
    }

    #pragma unroll
    for (int r = 0; r < 2; ++r)
        #pragma unroll
        for (int g = 0; g < 4; ++g) {
            float s = lsum[r][g];
            s += __shfl_xor(s, 1);
            s += __shfl_xor(s, 2);
            s += __shfl_xor(s, 4);
            s += __shfl_xor(s, 8);
            lsum[r][g] = s;
        }
    if (col == 0) {
        #pragma unroll
        for (int r = 0; r < 2; ++r)
            #pragma unroll
            for (int g = 0; g < 4; ++g)
                Lpart[wave][r * 16 + quad * 4 + g] = lsum[r][g];
    }
    __syncthreads();

    #pragma unroll
    for (int r = 0; r < 2; ++r) {
        float rinv[4];
        #pragma unroll
        for (int g = 0; g < 4; ++g) {
            float t = 0.f;
            #pragma unroll
            for (int w = 0; w < 16; ++w) t += Lpart[w][r * 16 + quad * 4 + g];
            rinv[g] = 1.0f / t;
        }
        #pragma unroll
        for (int c = 0; c < 2; ++c)
            #pragma unroll
            for (int g = 0; g < 4; ++g)
                Qlds[r * 16 + quad * 4 + g][wOcol + c * 16 + col] = f2bf(accO[r][c][g] * rinv[g]);
    }
    __syncthreads();

    f32x4 acc2[2][2];
    #pragma unroll
    for (int r = 0; r < 2; ++r)
        #pragma unroll
        for (int c = 0; c < 2; ++c) acc2[r][c] = (f32x4){0.f, 0.f, 0.f, 0.f};

    #pragma unroll
    for (int kk = 0; kk < 16; ++kk) {
        bf16x8 a0 = *(const bf16x8*)&Qlds[col][kk * 32 + quad * 8];
        bf16x8 a1 = *(const bf16x8*)&Qlds[16 + col][kk * 32 + quad * 8];
        #pragma unroll
        for (int c = 0; c < 2; ++c) {
            bf16x8 b = load8(Wv, (size_t)(wOcol + c * 16 + col) * 512 + kk * 32 + quad * 8, f32);
            acc2[0][c] = mfma16(a0, b, acc2[0][c]);
            acc2[1][c] = mfma16(a1, b, acc2[1][c]);
        }
    }

    #pragma unroll
    for (int r = 0; r < 2; ++r)
        #pragma unroll
        for (int c = 0; c < 2; ++c)
            #pragma unroll
            for (int g = 0; g < 4; ++g) {
                int m = q0 + r * 16 + quad * 4 + g;
                int n = wOcol + c * 16 + col;
                float v = acc2[r][c][g] + loadS(bv, n, f32);
                if (f32) ((float*)Out)[(size_t)m * DIM + n] = v;
                else     ((ushort_t*)Out)[(size_t)m * DIM + n] = f2bf(v);
            }
}

extern "C" void kernel_launch(void* const* d_in, const int* in_sizes, int n_in,
                              void* d_out, int out_size, void* d_ws, size_t ws_size,
                              hipStream_t stream)
{
    const void* emb = d_in[0];
    const void* Wqk = d_in[1];
    const void* bqk = d_in[2];
    const void* Wv  = d_in[3];
    const void* bv  = d_in[4];

    char* W = (char*)d_ws;
    int*      flag  = (int*)W;
    float*    lsumA = (float*)(W + 64);                        // 64 KB
    ushort_t* Wqkb  = (ushort_t*)(W + 64 + 65536);             // 512 KB
    ushort_t* Wvb   = Wqkb + (size_t)DIM * DIM;                // 512 KB
    ushort_t* bqkb  = Wvb + (size_t)DIM * DIM;                 // 1 KB
    ushort_t* bvb   = bqkb + DIM;                              // 1 KB
    ushort_t* embT  = bvb + DIM;                               // 8 MB
    ushort_t* Qws   = embT + (size_t)DIM * NTOK;               // 8 MB
    ushort_t* P0    = Qws + (size_t)DIM * NTOK;                // 8 MB
    ushort_t* P1    = P0 + (size_t)NTOK * DIM;                 // 8 MB

    const size_t needA = 64 + 65536 + 2 * (size_t)DIM * DIM * 2 + 2 * DIM * 2
                       + 4 * (size_t)NTOK * DIM * 2;           // ~33.1 MB
    const size_t needB = 64 + 2 * (size_t)NTOK * DIM * 2;      // 16.03 MB

    detect_kernel<<<dim3(1), dim3(64), 0, stream>>>((const ushort_t*)emb, flag);

    if (ws_size >= needA) {
        prep_kernel<<<dim3(128), dim3(256), 0, stream>>>(flag, Wqk, bqk, Wv, bv,
                                                         Wqkb, bqkb, Wvb, bvb);
        projqT_kernel<<<dim3(NTOK / 64), dim3(512), 0, stream>>>(flag, emb, Wqkb, bqkb,
                                                                 Qws, embT);
        attn64_kernel<<<dim3(256), dim3(1024), 0, stream>>>(Qws, embT, P0, P1, lsumA);
        finalize_kernel<<<dim3(NTOK / 64), dim3(512), 0, stream>>>(flag, P0, P1, lsumA,
                                                                   Wvb, bvb, d_out);
    } else if (ws_size >= needB) {
        ushort_t* embT2 = (ushort_t*)(W + 64);
        ushort_t* Qws2  = embT2 + (size_t)DIM * NTOK;
        transpose_kernel<<<dim3(128, 8), dim3(256), 0, stream>>>(flag, emb, embT2);
        projq_kernel<<<dim3(NTOK / 32), dim3(512), 0, stream>>>(flag, emb, Wqk, bqk, Qws2);
        attn_fused_kernel<1><<<dim3(NTOK / 32), dim3(1024), 0, stream>>>(
            flag, Qws2, embT2, Wv, bv, d_out);
    } else {
        ushort_t* Qsm = (ushort_t*)(W + 64);
        projq_kernel<<<dim3(NTOK / 32), dim3(512), 0, stream>>>(flag, emb, Wqk, bqk, Qsm);
        attn_fused_kernel<0><<<dim3(NTOK / 32), dim3(1024), 0, stream>>>(
            flag, Qsm, emb, Wv, bv, d_out);
    }
}